// Round 8
// baseline (2889.442 us; speedup 1.0000x reference)
//
#include <hip/hip_runtime.h>

// SimpleLSTM B=128,T=8192,H=96. R21 = R20 (best, 2875us) + f-gate rcp fold.
// Floor audit (R20 counters, per-active-SIMD): step 843 cyc = ds_read ~120
// + MFMA issue 290 (72 MFMA/CU fixed for 384x96 f16 GEMV; MX-fp8 escape
// checked dead: 16x16x128 MX = ~34.5 per-SIMD cyc -> 2-comp hi/lo split =
// 621 cyc >> 290, 1-comp fails precision) + tail ~40 + act trans chain ~130
// + select/xb/write ~50 + barrier ~90 + skew. Headroom ~5-8%, all slivers.
// R21 shave: fold f-gate's rcp into the cs update (exact algebra):
//   D2 = 1+2^-s1, N1 = 2L(uu-1), D1 = (uu+1)(1+vv)
//   cs_new = fg*cs + igg = (cs*D1 + N1*D2) * rcp(D1*D2)   [2 rcp -> 1]
// Trans 8 -> 7 (5 exp2 + 2 rcp), chain depth ~equal, overflow behavior
// identical to R20's passing form. Carried: 5 waves (4 gate + y/flush VALU
// wave), 2 batches in B cols, permuted W rows, exp2 prescale, x chunk-
// prefetch (f32x4/4 steps, compile-time parity), c'-domain state cs=2L*c,
// hoisted xb, fused h=(w-1)*rcp((w+1)(1+z)), named scalars, pinned A-frags,
// all-lane h write, y ring flush by 128, setprio(1) on gates.

#define T_LEN 8192
#define H_DIM 96
#define NTHR  320   // 5 waves: 4 gate waves + 1 y/flush wave
#define CHUNK 128
#define LOG2E 1.44269504f

typedef float    f32x4 __attribute__((ext_vector_type(4)));
typedef _Float16 half8 __attribute__((ext_vector_type(8)));

#define MFMA16(A, B, C)                                                        \
    __builtin_amdgcn_mfma_f32_16x16x32_f16(__builtin_bit_cast(half8, (A)),     \
                                           __builtin_bit_cast(half8, (B)),     \
                                           (C), 0, 0, 0)

__device__ __forceinline__ f32x4 load_afrag(const float* __restrict__ w_hh,
                                            int mt, int kt, int m, int quad) {
    half8 f;
    const int r = m & 3;                       // gate: 0=i 1=f 2=g 3=o
    const float scale = (r == 2) ? 2.0f * LOG2E : LOG2E;
    const int orig = r * 96 + 4 * mt + (m >> 2);
    const float* src = w_hh + orig * H_DIM + kt * 32 + quad * 8;
    #pragma unroll
    for (int jj = 0; jj < 8; ++jj) f[jj] = (_Float16)(scale * src[jj]);
    return __builtin_bit_cast(f32x4, f);
}

__global__ __launch_bounds__(NTHR, 2) void lstm_mfma21_kernel(
    const float* __restrict__ x,      // [B, T]
    const float* __restrict__ w_ih,   // [4H]
    const float* __restrict__ w_hh,   // [4H, H]
    const float* __restrict__ b_ih,   // [4H]
    const float* __restrict__ b_hh,   // [4H]
    const float* __restrict__ w_out,  // [H]
    const float* __restrict__ b_out,  // [1]
    float* __restrict__ y)            // [B, T]
{
    const int tid  = threadIdx.x;
    const int wv   = tid >> 6;        // wave 0..3 = gates, 4 = y/flush
    const int lane = tid & 63;
    const int m    = lane & 15;       // A-row / D-column index
    const int quad = lane >> 4;       // D row group / B K-chunk
    const int cc   = m & 7;           // within-batch column
    const int bsub = m >> 3;          // 0: batch 2b, 1: batch 2b+1

    __shared__ __align__(16) _Float16 h_s[2][2][H_DIM];       // [buf][bsub][cell]
    __shared__ __align__(16) float    y_buf[2][2][CHUNK];     // [bsub][ring][i]
    __shared__ __align__(16) float    x_s[2][T_LEN + 8];      // +8 pad: bank-split

    // ---- stage both batches' x into LDS
    {
        const float* xpair = x + (size_t)(2 * blockIdx.x) * T_LEN;
        for (int i = tid * 4; i < T_LEN; i += NTHR * 4) {
            *reinterpret_cast<f32x4*>(&x_s[0][i]) =
                *reinterpret_cast<const f32x4*>(&xpair[i]);
            *reinterpret_cast<f32x4*>(&x_s[1][i]) =
                *reinterpret_cast<const f32x4*>(&xpair[T_LEN + i]);
        }
    }

    // ---- A fragments (named, pinned). Gate wave wv owns tiles 6wv..6wv+5.
    const int mt0 = (wv < 4) ? 6 * wv : 0;
    f32x4 af00 = load_afrag(w_hh, mt0 + 0, 0, m, quad);
    f32x4 af01 = load_afrag(w_hh, mt0 + 0, 1, m, quad);
    f32x4 af02 = load_afrag(w_hh, mt0 + 0, 2, m, quad);
    f32x4 af10 = load_afrag(w_hh, mt0 + 1, 0, m, quad);
    f32x4 af11 = load_afrag(w_hh, mt0 + 1, 1, m, quad);
    f32x4 af12 = load_afrag(w_hh, mt0 + 1, 2, m, quad);
    f32x4 af20 = load_afrag(w_hh, mt0 + 2, 0, m, quad);
    f32x4 af21 = load_afrag(w_hh, mt0 + 2, 1, m, quad);
    f32x4 af22 = load_afrag(w_hh, mt0 + 2, 2, m, quad);
    f32x4 af30 = load_afrag(w_hh, mt0 + 3, 0, m, quad);
    f32x4 af31 = load_afrag(w_hh, mt0 + 3, 1, m, quad);
    f32x4 af32 = load_afrag(w_hh, mt0 + 3, 2, m, quad);
    f32x4 af40 = load_afrag(w_hh, mt0 + 4, 0, m, quad);
    f32x4 af41 = load_afrag(w_hh, mt0 + 4, 1, m, quad);
    f32x4 af42 = load_afrag(w_hh, mt0 + 4, 2, m, quad);
    f32x4 af50 = load_afrag(w_hh, mt0 + 5, 0, m, quad);
    f32x4 af51 = load_afrag(w_hh, mt0 + 5, 1, m, quad);
    f32x4 af52 = load_afrag(w_hh, mt0 + 5, 2, m, quad);
    f32x4 zero4 = {0.f, 0.f, 0.f, 0.f};
    asm volatile("" : "+v"(af00), "+v"(af01), "+v"(af02), "+v"(af10),
                      "+v"(af11), "+v"(af12), "+v"(af20));
    asm volatile("" : "+v"(af21), "+v"(af22), "+v"(af30), "+v"(af31),
                      "+v"(af32), "+v"(af40), "+v"(af41));
    asm volatile("" : "+v"(af42), "+v"(af50), "+v"(af51), "+v"(af52),
                      "+v"(zero4));

    // ---- y-wave only: w_out slices matching the B-frag k-positions (f32)
    f32x4 woa0 = {0,0,0,0}, woa1 = {0,0,0,0}, wob0 = {0,0,0,0},
          wob1 = {0,0,0,0}, woc0 = {0,0,0,0}, woc1 = {0,0,0,0};
    if (wv == 4) {
        woa0 = *reinterpret_cast<const f32x4*>(&w_out[quad * 8]);
        woa1 = *reinterpret_cast<const f32x4*>(&w_out[quad * 8 + 4]);
        wob0 = *reinterpret_cast<const f32x4*>(&w_out[32 + quad * 8]);
        wob1 = *reinterpret_cast<const f32x4*>(&w_out[32 + quad * 8 + 4]);
        woc0 = *reinterpret_cast<const f32x4*>(&w_out[64 + quad * 8]);
        woc1 = *reinterpret_cast<const f32x4*>(&w_out[64 + quad * 8 + 4]);
    }

    // ---- per-lane cell params (gate waves; exp2-domain prescaled)
    const int sel  = (cc >= 6) ? (cc - 6) : cc;
    const int cell = (wv < 4) ? (24 * wv + 4 * sel + quad) : 0;
    const bool s_b0 = sel & 1;
    const bool s_b1 = (sel >> 1) & 1;
    const bool s_b2 = (sel >> 2) & 1;
    const float bias_i = LOG2E * (b_ih[0 * H_DIM + cell] + b_hh[0 * H_DIM + cell]);
    const float bias_f = LOG2E * (b_ih[1 * H_DIM + cell] + b_hh[1 * H_DIM + cell]);
    const float bias_g = 2.0f * LOG2E * (b_ih[2 * H_DIM + cell] + b_hh[2 * H_DIM + cell]);
    const float bias_o = LOG2E * (b_ih[3 * H_DIM + cell] + b_hh[3 * H_DIM + cell]);
    const float wih_i  = LOG2E * w_ih[0 * H_DIM + cell];
    const float wih_f  = LOG2E * w_ih[1 * H_DIM + cell];
    const float wih_g  = 2.0f * LOG2E * w_ih[2 * H_DIM + cell];
    const float wih_o  = LOG2E * w_ih[3 * H_DIM + cell];
    const float bout   = b_out[0];
    float cs = 0.f;                   // cs = 2*log2e * c  (c'-domain state)
    if (tid < 2 * H_DIM) (&h_s[0][0][0])[tid] = (_Float16)0.0f;  // buf 0
    __syncthreads();

    if (wv < 4) __builtin_amdgcn_s_setprio(1);  // gates win SIMD0 arbitration

    // main loop in chunks of 4 steps; parity compile-time inside the chunk
    for (int it0 = 0; it0 < T_LEN; it0 += 4) {
        f32x4 xv = {0.f, 0.f, 0.f, 0.f};
        if (wv < 4)  // x[it0..it0+3] for this lane's batch, one b128 read
            xv = *reinterpret_cast<const f32x4*>(&x_s[bsub][it0]);

        #pragma unroll
        for (int u4 = 0; u4 < 4; ++u4) {
            const int it = it0 + u4;
            const int p = u4 & 1;     // == it & 1 (it0 multiple of 4)

            if (wv < 4) {
                // ------------- gate wave -------------
                const f32x4 b0 = *reinterpret_cast<const f32x4*>(&h_s[p][bsub][quad * 8]);
                const f32x4 b1 = *reinterpret_cast<const f32x4*>(&h_s[p][bsub][32 + quad * 8]);
                const f32x4 b2 = *reinterpret_cast<const f32x4*>(&h_s[p][bsub][64 + quad * 8]);
                const float x_cur = (u4 == 0) ? xv.x
                                  : (u4 == 1) ? xv.y
                                  : (u4 == 2) ? xv.z : xv.w;
                // hoisted x contribution (independent of MFMA results)
                const float xb_i = fmaf(x_cur, wih_i, bias_i);
                const float xb_f = fmaf(x_cur, wih_f, bias_f);
                const float xb_g = fmaf(x_cur, wih_g, bias_g);
                const float xb_o = fmaf(x_cur, wih_o, bias_o);

                f32x4 acc0 = MFMA16(af00, b0, zero4);
                f32x4 acc1 = MFMA16(af10, b0, zero4);
                f32x4 acc2 = MFMA16(af20, b0, zero4);
                f32x4 acc3 = MFMA16(af30, b0, zero4);
                f32x4 acc4 = MFMA16(af40, b0, zero4);
                f32x4 acc5 = MFMA16(af50, b0, zero4);
                acc0 = MFMA16(af01, b1, acc0);
                acc1 = MFMA16(af11, b1, acc1);
                acc2 = MFMA16(af21, b1, acc2);
                acc3 = MFMA16(af31, b1, acc3);
                acc4 = MFMA16(af41, b1, acc4);
                acc5 = MFMA16(af51, b1, acc5);
                acc0 = MFMA16(af02, b2, acc0);
                acc1 = MFMA16(af12, b2, acc1);
                acc2 = MFMA16(af22, b2, acc2);
                acc3 = MFMA16(af32, b2, acc3);
                acc4 = MFMA16(af42, b2, acc4);
                acc5 = MFMA16(af52, b2, acc5);

                // depth-3 binary select
                const f32x4 t0 = s_b0 ? acc1 : acc0;
                const f32x4 t1 = s_b0 ? acc3 : acc2;
                const f32x4 t2 = s_b0 ? acc5 : acc4;
                const f32x4 g4 = s_b2 ? t2 : (s_b1 ? t1 : t0);

                const float s0 = g4.x + xb_i;          // = log2e * pre_i
                const float s1 = g4.y + xb_f;          // = log2e * pre_f
                const float s2 = g4.z + xb_g;          // = 2log2e * pre_g
                const float s3 = g4.w + xb_o;          // = log2e * pre_o
                // trans block: 5 exp2 + 2 rcp
                const float uu  = __builtin_amdgcn_exp2f(s2);
                const float vv  = __builtin_amdgcn_exp2f(-s0);
                const float vvf = __builtin_amdgcn_exp2f(-s1);
                const float zz  = __builtin_amdgcn_exp2f(-s3);
                // fused cs update: cs' = fg*cs + ig*gg2
                //   N1 = 2L(uu-1), D1 = (uu+1)(1+vv), D2 = 1+vvf
                //   cs' = (cs*D1 + N1*D2) * rcp(D1*D2)
                const float N1 = fmaf(uu, 2.0f * LOG2E, -2.0f * LOG2E);
                const float D1 = (uu + 1.0f) * (1.0f + vv);
                const float D2 = 1.0f + vvf;
                const float num = fmaf(cs, D1, N1 * D2);
                cs = num * __builtin_amdgcn_rcpf(D1 * D2);   // cs = 2log2e*c
                // fused h = og*tanh(c) = (w-1) * rcp((w+1)(1+z))
                const float ww = __builtin_amdgcn_exp2f(cs);
                const float h  = (ww - 1.0f) *
                    __builtin_amdgcn_rcpf((ww + 1.0f) * (1.0f + zz));
                // all 64 lanes write; cc=6,7 bitwise-duplicate cc=0,1 (benign)
                h_s[p ^ 1][bsub][cell] = (_Float16)h;
            } else {
                // ------------- y / flush wave (VALU only) -------------
                const f32x4 b0 = *reinterpret_cast<const f32x4*>(&h_s[p][bsub][quad * 8]);
                const f32x4 b1 = *reinterpret_cast<const f32x4*>(&h_s[p][bsub][32 + quad * 8]);
                const f32x4 b2 = *reinterpret_cast<const f32x4*>(&h_s[p][bsub][64 + quad * 8]);
                const half8 hb0 = __builtin_bit_cast(half8, b0);
                const half8 hb1 = __builtin_bit_cast(half8, b1);
                const half8 hb2 = __builtin_bit_cast(half8, b2);
                float a0 = 0.f, a1 = 0.f, a2 = 0.f;   // 3 parallel chains
                #pragma unroll
                for (int j = 0; j < 4; ++j) {
                    a0 = fmaf((float)hb0[j], woa0[j], a0);
                    a1 = fmaf((float)hb1[j], wob0[j], a1);
                    a2 = fmaf((float)hb2[j], woc0[j], a2);
                }
                #pragma unroll
                for (int j = 0; j < 4; ++j) {
                    a0 = fmaf((float)hb0[4 + j], woa1[j], a0);
                    a1 = fmaf((float)hb1[4 + j], wob1[j], a1);
                    a2 = fmaf((float)hb2[4 + j], woc1[j], a2);
                }
                float acc = a0 + a1 + a2;             // this lane's 24 terms
                acc += __shfl_xor(acc, 32, 64);       // quad ^2
                acc += __shfl_xor(acc, 16, 64);       // quad ^1 -> full dot
                if ((lane == 0 || lane == 8) && it > 0)
                    y_buf[bsub][((it - 1) >> 7) & 1][(it - 1) & (CHUNK - 1)] =
                        acc + bout;
                // ring flush: at it = k*128 + 1 (k>=1), chunk [it-1-128, it-1)
                if (u4 == 1 && (it0 & (CHUNK - 1)) == 0 && it0 > 0) {
                    const int base = it0 - CHUNK;
                    const int pb   = (base >> 7) & 1;
                    const int bsel = lane >> 5;
                    const int li   = lane & 31;
                    const f32x4 v =
                        *reinterpret_cast<const f32x4*>(&y_buf[bsel][pb][li * 4]);
                    float* yrow = y + (size_t)(2 * blockIdx.x + bsel) * T_LEN;
                    *reinterpret_cast<f32x4*>(&yrow[base + li * 4]) = v;
                }
            }
            __syncthreads();  // h_s[p^1] + y_buf ready (5-wave barrier)
        }
    }

    // ---- epilogue: y_{T-1} + final ring flush
    if (wv == 4) {
        // h_{T-1} is in h_s[0] (T_LEN even)
        const f32x4 b0 = *reinterpret_cast<const f32x4*>(&h_s[0][bsub][quad * 8]);
        const f32x4 b1 = *reinterpret_cast<const f32x4*>(&h_s[0][bsub][32 + quad * 8]);
        const f32x4 b2 = *reinterpret_cast<const f32x4*>(&h_s[0][bsub][64 + quad * 8]);
        const half8 hb0 = __builtin_bit_cast(half8, b0);
        const half8 hb1 = __builtin_bit_cast(half8, b1);
        const half8 hb2 = __builtin_bit_cast(half8, b2);
        float a0 = 0.f, a1 = 0.f, a2 = 0.f;
        #pragma unroll
        for (int j = 0; j < 4; ++j) {
            a0 = fmaf((float)hb0[j], woa0[j], a0);
            a1 = fmaf((float)hb1[j], wob0[j], a1);
            a2 = fmaf((float)hb2[j], woc0[j], a2);
        }
        #pragma unroll
        for (int j = 0; j < 4; ++j) {
            a0 = fmaf((float)hb0[4 + j], woa1[j], a0);
            a1 = fmaf((float)hb1[4 + j], wob1[j], a1);
            a2 = fmaf((float)hb2[4 + j], woc1[j], a2);
        }
        float acc = a0 + a1 + a2;
        acc += __shfl_xor(acc, 32, 64);
        acc += __shfl_xor(acc, 16, 64);
        if (lane == 0 || lane == 8)
            y_buf[bsub][((T_LEN - 1) >> 7) & 1][(T_LEN - 1) & (CHUNK - 1)] =
                acc + bout;
    }
    __syncthreads();
    if (wv == 4) {  // flush last chunk [T_LEN-CHUNK, T_LEN)
        const int base = T_LEN - CHUNK;
        const int pb   = (base >> 7) & 1;
        const int bsel = lane >> 5;
        const int li   = lane & 31;
        const f32x4 v = *reinterpret_cast<const f32x4*>(&y_buf[bsel][pb][li * 4]);
        float* yrow = y + (size_t)(2 * blockIdx.x + bsel) * T_LEN;
        *reinterpret_cast<f32x4*>(&yrow[base + li * 4]) = v;
    }
}

extern "C" void kernel_launch(void* const* d_in, const int* in_sizes, int n_in,
                              void* d_out, int out_size, void* d_ws, size_t ws_size,
                              hipStream_t stream) {
    const float* x     = (const float*)d_in[0];
    const float* w_ih  = (const float*)d_in[1];
    const float* w_hh  = (const float*)d_in[2];
    const float* b_ih  = (const float*)d_in[3];
    const float* b_hh  = (const float*)d_in[4];
    const float* w_out = (const float*)d_in[5];
    const float* b_out = (const float*)d_in[6];
    float* y = (float*)d_out;

    const int NBLK = 64;  // 2 batches per block (packed into B columns)
    lstm_mfma21_kernel<<<dim3(NBLK), dim3(NTHR), 0, stream>>>(
        x, w_ih, w_hh, b_ih, b_hh, w_out, b_out, y);
}